// Round 3
// baseline (600.226 us; speedup 1.0000x reference)
//
#include <hip/hip_runtime.h>
#include <math.h>

// BundleAdjustmentModel: project N 3D points into V=64 camera views.
// out[v][n] = (u,v), u = -f*X/safe_z + cx, v = f*Y/safe_z + cy,
// [X,Y,Z] = R_v * p_n + t_v, R_v = Rx*Ry*Rz (euler xyz), t_v = (tx,ty,-(softplus(d)+0.25))
//
// Memory-bound: 256 MB writes vs 6 MB reads. In-situ write ceiling (harness
// poison fill) = 6.6 TB/s. Previous versions (view-loop + LDS constants)
// plateaued at ~2-2.5 TB/s effective regardless of wave count.
//
// This version streams like the fill kernel does:
//  - ONE view per block (grid.x=64 -> consecutive blocks share a point chunk,
//    keeping it L2-hot across XCDs; grid.y = point chunks).
//  - View constants (focal-folded rotation rows) live in registers. No LDS,
//    no __syncthreads, no ds_read on the critical path.
//  - PPT=8 consecutive points/thread: 6x global_load_dwordx4 in, ~120 VALU,
//    4x NONTEMPORAL global_store_dwordx4 out. Each block writes one
//    contiguous 16 KB span of one output row.
//  - Point data (6 MB) is re-read per view but stays resident in L3 (256 MB);
//    HBM read amplification is bounded by one fill per XCD L2.

#define NVIEW 64
#define BLOCK 256
#define PPT 8            // consecutive points per thread
#define Z_EPS 1e-4f

// native vector type for nontemporal stores (HIP_vector_type is rejected by
// __builtin_nontemporal_store)
typedef float floatx4 __attribute__((ext_vector_type(4)));

__device__ __forceinline__ float softplus_f(float x) {
    // stable: max(x,0) + log1p(exp(-|x|))
    return fmaxf(x, 0.0f) + log1pf(expf(-fabsf(x)));
}

__global__ __launch_bounds__(BLOCK) void ba_project_kernel(
    const float* __restrict__ points,          // (N,3)
    const float* __restrict__ euler,           // (V,3)
    const float* __restrict__ txy,             // (V,2)
    const float* __restrict__ tdr,             // (V,)
    const float* __restrict__ focal_raw,       // (1,)
    const int*   __restrict__ cxp,             // (1,)
    const int*   __restrict__ cyp,             // (1,)
    float2* __restrict__ out,                  // (V,N) float2
    int N)
{
    const int v = blockIdx.x;                  // one view per block

    // ---- per-view constants, all wave-uniform, all in registers ----
    const float focal = softplus_f(focal_raw[0]) + 50.0f;

    float ex = euler[v * 3 + 0];
    float ey = euler[v * 3 + 1];
    float ez = euler[v * 3 + 2];
    float sx, cx_, sy, cy_, sz, cz;
    sincosf(ex, &sx, &cx_);
    sincosf(ey, &sy, &cy_);
    sincosf(ez, &sz, &cz);
    // R = Rx @ Ry @ Rz
    float r00 = cy_ * cz;
    float r01 = -cy_ * sz;
    float r02 = sy;
    float r10 = cx_ * sz + sx * sy * cz;
    float r11 = cx_ * cz - sx * sy * sz;
    float r12 = -sx * cy_;
    float r20 = sx * sz - cx_ * sy * cz;
    float r21 = sx * cz + cx_ * sy * sz;
    float r22 = cx_ * cy_;

    float tx = txy[v * 2 + 0];
    float ty = txy[v * 2 + 1];
    float tz = -(softplus_f(tdr[v]) + 0.25f);

    // fold focal + sign: u = (-f*R0.p + -f*tx)/safe_z + cx ; v-row = +f*R1
    const float a0 = -focal * r00, a1 = -focal * r01, a2 = -focal * r02, a3 = -focal * tx;
    const float b0 =  focal * r10, b1 =  focal * r11, b2 =  focal * r12, b3 =  focal * ty;
    const float ccx = (float)cxp[0];
    const float ccy = (float)cyp[0];

    const int n0 = (blockIdx.y * BLOCK + threadIdx.x) * PPT;
    if (n0 >= N) return;

    float2* orow = out + (size_t)v * N + n0;

    if (n0 + PPT <= N) {
        // fast path: 8 consecutive points = 24 floats = 6 aligned float4 loads
        // (byte offset n0*12 = 96*t, multiple of 16)
        const float4* src = (const float4*)(points + (size_t)n0 * 3);
        float4 L0 = src[0], L1 = src[1], L2 = src[2];
        float4 L3 = src[3], L4 = src[4], L5 = src[5];
        const float P[PPT][3] = {
            {L0.x, L0.y, L0.z}, {L0.w, L1.x, L1.y},
            {L1.z, L1.w, L2.x}, {L2.y, L2.z, L2.w},
            {L3.x, L3.y, L3.z}, {L3.w, L4.x, L4.y},
            {L4.z, L4.w, L5.x}, {L5.y, L5.z, L5.w}};

        float uv[PPT * 2];
#pragma unroll
        for (int k = 0; k < PPT; ++k) {
            float X = fmaf(a0, P[k][0], fmaf(a1, P[k][1], fmaf(a2, P[k][2], a3)));
            float Y = fmaf(b0, P[k][0], fmaf(b1, P[k][1], fmaf(b2, P[k][2], b3)));
            float Z = fmaf(r20, P[k][0], fmaf(r21, P[k][1], fmaf(r22, P[k][2], tz)));
            float sg = (Z >= 0.0f) ? 1.0f : -1.0f;
            float t  = __builtin_amdgcn_rcpf(sg * fmaxf(fabsf(Z), Z_EPS));
            uv[k * 2 + 0] = fmaf(X, t, ccx);
            uv[k * 2 + 1] = fmaf(Y, t, ccy);
        }

        // 4x nontemporal dwordx4: wave writes 2 KB contiguous, 16B aligned
        floatx4* o4 = (floatx4*)orow;
#pragma unroll
        for (int k = 0; k < PPT / 2; ++k) {
            floatx4 val;
            val.x = uv[4 * k + 0];
            val.y = uv[4 * k + 1];
            val.z = uv[4 * k + 2];
            val.w = uv[4 * k + 3];
            __builtin_nontemporal_store(val, &o4[k]);
        }
    } else {
        // tail path (unused for N=500000, kept general)
        for (int k = 0; k < PPT && n0 + k < N; ++k) {
            float x = points[(size_t)(n0 + k) * 3 + 0];
            float y = points[(size_t)(n0 + k) * 3 + 1];
            float z = points[(size_t)(n0 + k) * 3 + 2];
            float X = fmaf(a0, x, fmaf(a1, y, fmaf(a2, z, a3)));
            float Y = fmaf(b0, x, fmaf(b1, y, fmaf(b2, z, b3)));
            float Z = fmaf(r20, x, fmaf(r21, y, fmaf(r22, z, tz)));
            float sg = (Z >= 0.0f) ? 1.0f : -1.0f;
            float t  = __builtin_amdgcn_rcpf(sg * fmaxf(fabsf(Z), Z_EPS));
            orow[k] = make_float2(fmaf(X, t, ccx), fmaf(Y, t, ccy));
        }
    }
}

extern "C" void kernel_launch(void* const* d_in, const int* in_sizes, int n_in,
                              void* d_out, int out_size, void* d_ws, size_t ws_size,
                              hipStream_t stream) {
    const float* points    = (const float*)d_in[0];
    const float* euler     = (const float*)d_in[1];
    const float* txy       = (const float*)d_in[2];
    const float* tdr       = (const float*)d_in[3];
    const float* focal_raw = (const float*)d_in[4];
    const int*   cxp       = (const int*)d_in[5];
    const int*   cyp       = (const int*)d_in[6];

    const int N = in_sizes[0] / 3;
    const int chunk = BLOCK * PPT;                       // 2048 points per block
    const int nchunks = (N + chunk - 1) / chunk;
    dim3 grid(NVIEW, nchunks, 1);

    ba_project_kernel<<<grid, dim3(BLOCK, 1, 1), 0, stream>>>(
        points, euler, txy, tdr, focal_raw, cxp, cyp, (float2*)d_out, N);
}

// Round 4
// 304.459 us; speedup vs baseline: 1.9715x; 1.9715x over previous
//
#include <hip/hip_runtime.h>
#include <math.h>

// BundleAdjustmentModel: project N 3D points into V=64 camera views.
// out[v][n] = (u,v), u = -f*X/safe_z + cx, v = f*Y/safe_z + cy,
// [X,Y,Z] = R_v * p_n + t_v, R_v = Rx*Ry*Rz (euler xyz), t_v = (tx,ty,-(softplus(d)+0.25))
//
// Memory-bound: 256 MB writes vs 6 MB reads. In-situ write ceiling (harness
// poison fill) = 6.6 TB/s.
//
// Round-3 lesson (counter-evidenced): __builtin_nontemporal_store caused
// WRITE_SIZE = 674 MB for a 256 MB output (2.63x write amplification --
// nt stores defeat L2 write-combining, partial lines evicted to HBM).
// FETCH_SIZE was only 23 MB, confirming L3 absorbs the 64x point re-read.
// => keep the streaming structure, use PLAIN stores so L2 combines the
//    wave's contiguous 4 KB into full lines.
//
// Structure:
//  - ONE view per block (grid.x=64 -> consecutive blocks share a point chunk,
//    L2-hot across XCDs; grid.y = point chunks).
//  - View constants (focal-folded rotation rows) in registers. No LDS,
//    no __syncthreads, no ds_read.
//  - PPT=8 consecutive points/thread: 6x global_load_dwordx4 in, ~120 VALU,
//    4x global_store_dwordx4 out; each block writes one contiguous 16 KB
//    span of one output row.

#define NVIEW 64
#define BLOCK 256
#define PPT 8            // consecutive points per thread
#define Z_EPS 1e-4f

__device__ __forceinline__ float softplus_f(float x) {
    // stable: max(x,0) + log1p(exp(-|x|))
    return fmaxf(x, 0.0f) + log1pf(expf(-fabsf(x)));
}

__global__ __launch_bounds__(BLOCK) void ba_project_kernel(
    const float* __restrict__ points,          // (N,3)
    const float* __restrict__ euler,           // (V,3)
    const float* __restrict__ txy,             // (V,2)
    const float* __restrict__ tdr,             // (V,)
    const float* __restrict__ focal_raw,       // (1,)
    const int*   __restrict__ cxp,             // (1,)
    const int*   __restrict__ cyp,             // (1,)
    float2* __restrict__ out,                  // (V,N) float2
    int N)
{
    const int v = blockIdx.x;                  // one view per block

    // ---- per-view constants, all wave-uniform, all in registers ----
    const float focal = softplus_f(focal_raw[0]) + 50.0f;

    float ex = euler[v * 3 + 0];
    float ey = euler[v * 3 + 1];
    float ez = euler[v * 3 + 2];
    float sx, cx_, sy, cy_, sz, cz;
    sincosf(ex, &sx, &cx_);
    sincosf(ey, &sy, &cy_);
    sincosf(ez, &sz, &cz);
    // R = Rx @ Ry @ Rz
    float r00 = cy_ * cz;
    float r01 = -cy_ * sz;
    float r02 = sy;
    float r10 = cx_ * sz + sx * sy * cz;
    float r11 = cx_ * cz - sx * sy * sz;
    float r12 = -sx * cy_;
    float r20 = sx * sz - cx_ * sy * cz;
    float r21 = sx * cz + cx_ * sy * sz;
    float r22 = cx_ * cy_;

    float tx = txy[v * 2 + 0];
    float ty = txy[v * 2 + 1];
    float tz = -(softplus_f(tdr[v]) + 0.25f);

    // fold focal + sign: u = (-f*R0.p + -f*tx)/safe_z + cx ; v-row = +f*R1
    const float a0 = -focal * r00, a1 = -focal * r01, a2 = -focal * r02, a3 = -focal * tx;
    const float b0 =  focal * r10, b1 =  focal * r11, b2 =  focal * r12, b3 =  focal * ty;
    const float ccx = (float)cxp[0];
    const float ccy = (float)cyp[0];

    const int n0 = (blockIdx.y * BLOCK + threadIdx.x) * PPT;
    if (n0 >= N) return;

    float2* orow = out + (size_t)v * N + n0;

    if (n0 + PPT <= N) {
        // fast path: 8 consecutive points = 24 floats = 6 aligned float4 loads
        // (byte offset n0*12 = 96*t, multiple of 16)
        const float4* src = (const float4*)(points + (size_t)n0 * 3);
        float4 L0 = src[0], L1 = src[1], L2 = src[2];
        float4 L3 = src[3], L4 = src[4], L5 = src[5];
        const float P[PPT][3] = {
            {L0.x, L0.y, L0.z}, {L0.w, L1.x, L1.y},
            {L1.z, L1.w, L2.x}, {L2.y, L2.z, L2.w},
            {L3.x, L3.y, L3.z}, {L3.w, L4.x, L4.y},
            {L4.z, L4.w, L5.x}, {L5.y, L5.z, L5.w}};

        float uv[PPT * 2];
#pragma unroll
        for (int k = 0; k < PPT; ++k) {
            float X = fmaf(a0, P[k][0], fmaf(a1, P[k][1], fmaf(a2, P[k][2], a3)));
            float Y = fmaf(b0, P[k][0], fmaf(b1, P[k][1], fmaf(b2, P[k][2], b3)));
            float Z = fmaf(r20, P[k][0], fmaf(r21, P[k][1], fmaf(r22, P[k][2], tz)));
            float sg = (Z >= 0.0f) ? 1.0f : -1.0f;
            float t  = __builtin_amdgcn_rcpf(sg * fmaxf(fabsf(Z), Z_EPS));
            uv[k * 2 + 0] = fmaf(X, t, ccx);
            uv[k * 2 + 1] = fmaf(Y, t, ccy);
        }

        // 4x plain dwordx4 stores: wave writes 4 KB contiguous, 16B aligned;
        // L2 write-combines into full lines (NT stores broke this: 2.63x
        // HBM write amplification, see header).
        float4* o4 = (float4*)orow;
#pragma unroll
        for (int k = 0; k < PPT / 2; ++k) {
            o4[k] = make_float4(uv[4 * k + 0], uv[4 * k + 1],
                                uv[4 * k + 2], uv[4 * k + 3]);
        }
    } else {
        // tail path (unused for N=500000, kept general)
        for (int k = 0; k < PPT && n0 + k < N; ++k) {
            float x = points[(size_t)(n0 + k) * 3 + 0];
            float y = points[(size_t)(n0 + k) * 3 + 1];
            float z = points[(size_t)(n0 + k) * 3 + 2];
            float X = fmaf(a0, x, fmaf(a1, y, fmaf(a2, z, a3)));
            float Y = fmaf(b0, x, fmaf(b1, y, fmaf(b2, z, b3)));
            float Z = fmaf(r20, x, fmaf(r21, y, fmaf(r22, z, tz)));
            float sg = (Z >= 0.0f) ? 1.0f : -1.0f;
            float t  = __builtin_amdgcn_rcpf(sg * fmaxf(fabsf(Z), Z_EPS));
            orow[k] = make_float2(fmaf(X, t, ccx), fmaf(Y, t, ccy));
        }
    }
}

extern "C" void kernel_launch(void* const* d_in, const int* in_sizes, int n_in,
                              void* d_out, int out_size, void* d_ws, size_t ws_size,
                              hipStream_t stream) {
    const float* points    = (const float*)d_in[0];
    const float* euler     = (const float*)d_in[1];
    const float* txy       = (const float*)d_in[2];
    const float* tdr       = (const float*)d_in[3];
    const float* focal_raw = (const float*)d_in[4];
    const int*   cxp       = (const int*)d_in[5];
    const int*   cyp       = (const int*)d_in[6];

    const int N = in_sizes[0] / 3;
    const int chunk = BLOCK * PPT;                       // 2048 points per block
    const int nchunks = (N + chunk - 1) / chunk;
    dim3 grid(NVIEW, nchunks, 1);

    ba_project_kernel<<<grid, dim3(BLOCK, 1, 1), 0, stream>>>(
        points, euler, txy, tdr, focal_raw, cxp, cyp, (float2*)d_out, N);
}

// Round 5
// 261.222 us; speedup vs baseline: 2.2978x; 1.1655x over previous
//
#include <hip/hip_runtime.h>
#include <math.h>

// BundleAdjustmentModel: project N 3D points into V=64 camera views.
// out[v][n] = (u,v), u = -f*X/safe_z + cx, v = f*Y/safe_z + cy,
// [X,Y,Z] = R_v * p_n + t_v, R_v = Rx*Ry*Rz (euler xyz), t_v = (tx,ty,-(softplus(d)+0.25))
//
// Evidence so far (counter-backed):
//  - NT stores: 2.63x HBM write amplification (WRITE_SIZE 674 MB vs 256 MB) -> never.
//  - FETCH_SIZE stays ~23 MB even at 64x point re-read: L3 absorbs reads from HBM,
//    but kernel time still scales with re-read volume (r0 1x ~105us, r1 4x ~122us,
//    r4 64x ~150us) -> L2/L3 *read path* contends with the write stream.
//  => winning structure = round 0: all 64 views per thread, points loaded ONCE,
//     per-view constants broadcast from LDS (conflict-free).
//
// This version = round-0 structure with exactly one change: each thread owns a
// CONSECUTIVE point pair, so each view iteration emits ONE float4 store
// (16 B/lane, wave writes contiguous 1 KB per instruction, half the store
// instructions of round 0's 2x float2), with focal folded into the LDS rows.

#define NVIEW 64
#define BLOCK 256
#define Z_EPS 1e-4f

__device__ __forceinline__ float softplus_f(float x) {
    // stable: max(x,0) + log1p(exp(-|x|))
    return fmaxf(x, 0.0f) + log1pf(expf(-fabsf(x)));
}

__global__ __launch_bounds__(BLOCK) void ba_project_kernel(
    const float* __restrict__ points,          // (N,3)
    const float* __restrict__ euler,           // (V,3)
    const float* __restrict__ txy,             // (V,2)
    const float* __restrict__ tdr,             // (V,)
    const float* __restrict__ focal_raw,       // (1,)
    const int*   __restrict__ cxp,             // (1,)
    const int*   __restrict__ cyp,             // (1,)
    float2* __restrict__ out,                  // (V,N) float2
    int N)
{
    // Per-view constants: rows [-f*R0|-f*tx], [f*R1|f*ty], [R2|tz],
    // 3 float4s per view. Broadcast ds_read_b128 -> conflict-free.
    __shared__ float4 vd[NVIEW * 3];

    const int tid = threadIdx.x;
    const float focal = softplus_f(focal_raw[0]) + 50.0f;

    if (tid < NVIEW) {
        float ex = euler[tid * 3 + 0];
        float ey = euler[tid * 3 + 1];
        float ez = euler[tid * 3 + 2];
        float sx, cx_, sy, cy_, sz, cz;
        sincosf(ex, &sx, &cx_);
        sincosf(ey, &sy, &cy_);
        sincosf(ez, &sz, &cz);
        // R = Rx @ Ry @ Rz
        float r00 = cy_ * cz;
        float r01 = -cy_ * sz;
        float r02 = sy;
        float r10 = cx_ * sz + sx * sy * cz;
        float r11 = cx_ * cz - sx * sy * sz;
        float r12 = -sx * cy_;
        float r20 = sx * sz - cx_ * sy * cz;
        float r21 = sx * cz + cx_ * sy * sz;
        float r22 = cx_ * cy_;

        float tx = txy[tid * 2 + 0];
        float ty = txy[tid * 2 + 1];
        float tz = -(softplus_f(tdr[tid]) + 0.25f);

        vd[tid * 3 + 0] = make_float4(-focal * r00, -focal * r01, -focal * r02, -focal * tx);
        vd[tid * 3 + 1] = make_float4( focal * r10,  focal * r11,  focal * r12,  focal * ty);
        vd[tid * 3 + 2] = make_float4(r20, r21, r22, tz);
    }
    __syncthreads();

    const float ccx = (float)cxp[0];
    const float ccy = (float)cyp[0];

    // Each thread owns the consecutive point pair {2*pair, 2*pair+1};
    // points loaded ONCE, reused across all 64 views.
    const int pair = blockIdx.x * BLOCK + tid;
    const int n0 = pair * 2;
    if (n0 >= N) return;
    const bool full = (n0 + 1 < N);   // N=500000 even; guard stays general

    const float2* p2 = (const float2*)points;   // 8B-aligned pair loads
    float2 a = p2[pair * 3 + 0];
    float2 b, c;
    if (full) {
        b = p2[pair * 3 + 1];
        c = p2[pair * 3 + 2];
    } else {
        b = make_float2(points[(size_t)n0 * 3 + 2], 0.0f);  // z0 only, no OOB
        c = make_float2(0.0f, 0.0f);
    }
    const float x0 = a.x, y0 = a.y, z0 = b.x;
    const float x1 = b.y, y1 = c.x, z1 = c.y;

    float2* orow = out + n0;   // + v*N added in-loop

    for (int v = 0; v < NVIEW; ++v) {
        float4 A = vd[v * 3 + 0];
        float4 B = vd[v * 3 + 1];
        float4 C = vd[v * 3 + 2];

        // point 0
        float X0 = fmaf(A.x, x0, fmaf(A.y, y0, fmaf(A.z, z0, A.w)));
        float Y0 = fmaf(B.x, x0, fmaf(B.y, y0, fmaf(B.z, z0, B.w)));
        float Z0 = fmaf(C.x, x0, fmaf(C.y, y0, fmaf(C.z, z0, C.w)));
        float sg0 = (Z0 >= 0.0f) ? 1.0f : -1.0f;
        float t0  = __builtin_amdgcn_rcpf(sg0 * fmaxf(fabsf(Z0), Z_EPS));
        float u0 = fmaf(X0, t0, ccx);
        float w0 = fmaf(Y0, t0, ccy);

        // point 1
        float X1 = fmaf(A.x, x1, fmaf(A.y, y1, fmaf(A.z, z1, A.w)));
        float Y1 = fmaf(B.x, x1, fmaf(B.y, y1, fmaf(B.z, z1, B.w)));
        float Z1 = fmaf(C.x, x1, fmaf(C.y, y1, fmaf(C.z, z1, C.w)));
        float sg1 = (Z1 >= 0.0f) ? 1.0f : -1.0f;
        float t1  = __builtin_amdgcn_rcpf(sg1 * fmaxf(fabsf(Z1), Z_EPS));
        float u1 = fmaf(X1, t1, ccx);
        float w1 = fmaf(Y1, t1, ccy);

        if (full) {
            // one 16B store per view: wave writes contiguous, 16B-aligned 1 KB
            *(float4*)(orow + (size_t)v * N) = make_float4(u0, w0, u1, w1);
        } else {
            orow[(size_t)v * N] = make_float2(u0, w0);
        }
    }
}

extern "C" void kernel_launch(void* const* d_in, const int* in_sizes, int n_in,
                              void* d_out, int out_size, void* d_ws, size_t ws_size,
                              hipStream_t stream) {
    const float* points    = (const float*)d_in[0];
    const float* euler     = (const float*)d_in[1];
    const float* txy       = (const float*)d_in[2];
    const float* tdr       = (const float*)d_in[3];
    const float* focal_raw = (const float*)d_in[4];
    const int*   cxp       = (const int*)d_in[5];
    const int*   cyp       = (const int*)d_in[6];

    const int N = in_sizes[0] / 3;
    const int pairs = (N + 1) / 2;
    const int blocks = (pairs + BLOCK - 1) / BLOCK;

    ba_project_kernel<<<blocks, dim3(BLOCK, 1, 1), 0, stream>>>(
        points, euler, txy, tdr, focal_raw, cxp, cyp, (float2*)d_out, N);
}